// Round 1
// baseline (678.141 us; speedup 1.0000x reference)
//
#include <hip/hip_runtime.h>
#include <math.h>

#define N 512
#define T 32
#define NROUND (N / T)

// softmin with gamma=0.1:  sm(a,b) = -g*ln(e^(-a/g) + e^(-b/g))
// online form: track m (running min), s (sum of exp2(-S*(x-m))), S = 10*log2(e)
#define SM_S 14.426950408889634f   // (1/gamma) * log2(e)
#define SM_C 0.06931471805599453f  // gamma * ln(2)

__device__ __forceinline__ void sm_update(float v, float& m, float& s) {
    float d = v - m;
    float e = __builtin_amdgcn_exp2f(-SM_S * fabsf(d));
    float f1 = d < 0.0f ? e : 1.0f;     // rescale old sum if new min
    float f2 = d < 0.0f ? 1.0f : e;     // new term
    s = fmaf(s, f1, f2);
    m = fminf(m, v);
}
__device__ __forceinline__ float sm_final(float m, float s) {
    return fmaf(-SM_C, __builtin_amdgcn_logf(s), m);  // m - g*ln(s)
}

// ---------------------------------------------------------------------------
// init: w0 = distances/(soft_adj+1e-4) * (1-eye); accumulate static loss terms
// acc[0]=loss_cost acc[1]=entropy acc[2]=mask acc[3]=utility
// ---------------------------------------------------------------------------
__device__ __forceinline__ void wave_atomic_add(float* p, float v) {
    #pragma unroll
    for (int o = 32; o > 0; o >>= 1) v += __shfl_down(v, o);
    if ((threadIdx.x & 63) == 0) atomicAdd(p, v);
}

__global__ __launch_bounds__(256) void init_kernel(
        const float* __restrict__ sa, const float* __restrict__ oa,
        const float* __restrict__ di, float* __restrict__ w,
        float* __restrict__ acc) {
    float lc = 0.0f, en = 0.0f, mk = 0.0f;
    for (int idx = blockIdx.x * 256 + threadIdx.x; idx < N * N;
         idx += gridDim.x * 256) {
        int i = idx >> 9, j = idx & (N - 1);
        float s = sa[idx], d = di[idx];
        w[idx] = (i == j) ? 0.0f : d / (s + 1e-4f);
        lc = fmaf(s, d, lc);
        float inv = ((i == j) ? 1.0f : 0.0f) - s;
        float t2 = s * inv;
        en = fmaf(t2, t2, en);
        mk = fmaf(s, 1.0f - oa[idx], mk);
    }
    wave_atomic_add(&acc[0], lc);
    wave_atomic_add(&acc[1], en);
    wave_atomic_add(&acc[2], mk);
}

// ---------------------------------------------------------------------------
// diag: exact pivots of the TxT diagonal block, 1 wave.
// lanes 0..31  own column j' of D:  D[k][j'] = w^(k)[k0+k, k0+j']
// lanes 32..63 own row    i' of E:  E[i'][k] = w^(k)[k0+i', k0+k]
// wavefront over mm: materialize elem mm, broadcast via shfl, update k>mm.
// ---------------------------------------------------------------------------
__global__ __launch_bounds__(64) void diag_kernel(
        const float* __restrict__ w, float* __restrict__ Dg,
        float* __restrict__ Eg, int k0) {
    const int lane = threadIdx.x;
    const bool isD = lane < T;
    const int q = isD ? lane : (lane - T);
    float mst[T], sst[T];
    #pragma unroll
    for (int k = 0; k < T; ++k) {
        int rr = isD ? (k0 + k) : (k0 + q);
        int cc = isD ? (k0 + q) : (k0 + k);
        mst[k] = w[rr * N + cc];
        sst[k] = 1.0f;
    }
    const int srcbase = isD ? T : 0;
    #pragma unroll
    for (int mm = 0; mm < T; ++mm) {
        float val = sm_final(mst[mm], sst[mm]);
        if (isD) Dg[mm * T + q] = val;      // D[mm][j']
        else     Eg[q * T + mm] = val;      // E[i'][mm]
        #pragma unroll
        for (int k = mm + 1; k < T; ++k) {
            // D-lane elem k: needs E[k][mm] (from lane 32+k) + own D[mm][j']
            // E-lane elem k: needs D[mm][k] (from lane k)    + own E[i'][mm]
            float o = __shfl(val, srcbase + k);
            sm_update(o + val, mst[k], sst[k]);
        }
    }
}

// ---------------------------------------------------------------------------
// panels: blocks 0,1 -> rowpiv[T][N] (thread = column j, reads E)
//         blocks 2,3 -> colpiv[N][T] (thread = row i,    reads D)
// ---------------------------------------------------------------------------
__global__ __launch_bounds__(256) void panel_kernel(
        const float* __restrict__ w, const float* __restrict__ Dg,
        const float* __restrict__ Eg, float* __restrict__ rowpiv,
        float* __restrict__ colpiv, int k0) {
    __shared__ float P[T * T];
    __shared__ float WT[256][T + 1];
    const int t = threadIdx.x;
    const bool isRow = blockIdx.x < 2;
    const int base = (blockIdx.x & 1) * 256;
    const float* src = isRow ? Eg : Dg;
    for (int idx = t; idx < T * T; idx += 256) P[idx] = src[idx];
    if (!isRow) {
        // coalesced stage of w[base..base+255][k0..k0+31]
        for (int idx = t; idx < 256 * T; idx += 256) {
            int row = idx >> 5, c = idx & (T - 1);
            WT[row][c] = w[(base + row) * N + k0 + c];
        }
    }
    __syncthreads();

    float mst[T], sst[T];
    if (isRow) {
        const int j = base + t;
        #pragma unroll
        for (int k = 0; k < T; ++k) { mst[k] = w[(k0 + k) * N + j]; sst[k] = 1.0f; }
        #pragma unroll
        for (int mm = 0; mm < T; ++mm) {
            float val = sm_final(mst[mm], sst[mm]);
            rowpiv[mm * N + j] = val;              // coalesced
            #pragma unroll
            for (int k = mm + 1; k < T; ++k)
                sm_update(P[k * T + mm] + val, mst[k], sst[k]);  // E[k][mm]+rowpiv[mm][j]
        }
    } else {
        #pragma unroll
        for (int k = 0; k < T; ++k) { mst[k] = WT[t][k]; sst[k] = 1.0f; }
        float piv[T];
        #pragma unroll
        for (int mm = 0; mm < T; ++mm) {
            float val = sm_final(mst[mm], sst[mm]);
            piv[mm] = val;
            #pragma unroll
            for (int k = mm + 1; k < T; ++k)
                sm_update(val + P[mm * T + k], mst[k], sst[k]);  // colpiv[i][mm]+D[mm][k]
        }
        __syncthreads();
        #pragma unroll
        for (int k = 0; k < T; ++k) WT[t][k] = piv[k];
        __syncthreads();
        for (int idx = t; idx < 256 * T; idx += 256) {   // coalesced store
            int row = idx >> 5, c = idx & (T - 1);
            colpiv[(base + row) * T + c] = WT[row][c];
        }
    }
}

// ---------------------------------------------------------------------------
// sweep: apply the T-step chain uniformly to every element.
// grid 512 = 64 row-groups x 8 col-groups; tile 8x64; thread -> 2 elements.
// ---------------------------------------------------------------------------
__global__ __launch_bounds__(256) void sweep_kernel(
        float* __restrict__ w, const float* __restrict__ rowpiv,
        const float* __restrict__ colpiv) {
    const int tr = blockIdx.x >> 3, tc = blockIdx.x & 7;
    const int r0 = tr * 8, c0 = tc * 64;
    __shared__ float RP[T][64];
    __shared__ float CP[8][T];
    const int t = threadIdx.x;
    for (int idx = t; idx < T * 64; idx += 256) {
        int k = idx >> 6, c = idx & 63;
        RP[k][c] = rowpiv[k * N + c0 + c];
    }
    {
        int r = t >> 5, k = t & (T - 1);
        CP[r][k] = colpiv[(r0 + r) * T + k];
    }
    __syncthreads();
    const int rr = t >> 6;       // 0..3
    const int c = t & 63;
    float* wp0 = &w[(r0 + rr) * N + c0 + c];
    float* wp1 = &w[(r0 + rr + 4) * N + c0 + c];
    float m0 = *wp0, s0 = 1.0f;
    float m1 = *wp1, s1 = 1.0f;
    #pragma unroll
    for (int k = 0; k < T; ++k) {
        float rp = RP[k][c];
        sm_update(CP[rr][k] + rp, m0, s0);
        sm_update(CP[rr + 4][k] + rp, m1, s1);
    }
    *wp0 = sm_final(m0, s0);
    *wp1 = sm_final(m1, s1);
}

// ---------------------------------------------------------------------------
// utility-gain pass over final shortest paths
// ---------------------------------------------------------------------------
__global__ __launch_bounds__(256) void util_kernel(
        const float* __restrict__ w, const float* __restrict__ di,
        const float* __restrict__ fl, float* __restrict__ acc) {
    float ug = 0.0f;
    for (int idx = blockIdx.x * 256 + threadIdx.x; idx < N * N;
         idx += gridDim.x * 256) {
        int i = idx >> 9, j = idx & (N - 1);
        float sp = w[idx], d = di[idx];
        float er = __expf(-0.005f * sp);      // exp(UTILITY_SCALE*sp*PRIORITY_RAIL)
        float eb = __expf(-0.01f * d);
        float choice = er / (er + eb);
        float x = d - 0.5f * sp;
        float elu = x > 0.0f ? x : (__expf(x) - 1.0f);
        float dsv = (i == j) ? 0.0f : (elu + 1.0f);
        ug = fmaf(fl[idx] * choice, dsv, ug);
    }
    wave_atomic_add(&acc[3], ug);
}

__global__ void combine_kernel(const float* __restrict__ acc,
                               const int* __restrict__ epoch,
                               float* __restrict__ out) {
    if (threadIdx.x == 0 && blockIdx.x == 0) {
        int e = *epoch;
        // searchsorted([0,100], e, right) -> (e>=0)+(e>=100); levels {0.1,0.5,1.0}
        int idx = (e >= 0 ? 1 : 0) + (e >= 100 ? 1 : 0);
        float scale = idx == 0 ? 0.1f : (idx == 1 ? 0.5f : 1.0f);
        out[0] = acc[0] + acc[3] + scale * acc[1] + scale * acc[2];
    }
}

extern "C" void kernel_launch(void* const* d_in, const int* in_sizes, int n_in,
                              void* d_out, int out_size, void* d_ws, size_t ws_size,
                              hipStream_t stream) {
    const float* sa = (const float*)d_in[0];
    const float* oa = (const float*)d_in[1];
    const float* di = (const float*)d_in[2];
    const float* fl = (const float*)d_in[3];
    const int* ep = (const int*)d_in[4];
    float* out = (float*)d_out;

    float* ws = (float*)d_ws;
    float* w      = ws;                 // 262144
    float* rowpiv = ws + 262144;        // 16384  (T x N)
    float* colpiv = ws + 278528;        // 16384  (N x T)
    float* Dg     = ws + 294912;        // 1024
    float* Eg     = ws + 295936;        // 1024
    float* acc    = ws + 296960;        // 4

    hipMemsetAsync(acc, 0, 4 * sizeof(float), stream);
    init_kernel<<<512, 256, 0, stream>>>(sa, oa, di, w, acc);
    for (int r = 0; r < NROUND; ++r) {
        int k0 = r * T;
        diag_kernel<<<1, 64, 0, stream>>>(w, Dg, Eg, k0);
        panel_kernel<<<4, 256, 0, stream>>>(w, Dg, Eg, rowpiv, colpiv, k0);
        sweep_kernel<<<512, 256, 0, stream>>>(w, rowpiv, colpiv);
    }
    util_kernel<<<512, 256, 0, stream>>>(w, di, fl, acc);
    combine_kernel<<<1, 64, 0, stream>>>(acc, ep, out);
}

// Round 2
// 509.149 us; speedup vs baseline: 1.3319x; 1.3319x over previous
//
#include <hip/hip_runtime.h>
#include <math.h>

#define N 512
#define T 32
#define NROUND (N / T)

// softmin with gamma=0.1:  sm(a,b) = -g*ln(e^(-a/g) + e^(-b/g))
// online form: track m (running min), s (sum of exp2(-S*(x-m))), S = 10*log2(e)
#define SM_S 14.426950408889634f   // (1/gamma) * log2(e)
#define SM_C 0.06931471805599453f  // gamma * ln(2)

__device__ __forceinline__ void sm_update(float v, float& m, float& s) {
    float d = v - m;
    float e = __builtin_amdgcn_exp2f(-SM_S * fabsf(d));
    float f1 = d < 0.0f ? e : 1.0f;     // rescale old sum if new min
    float f2 = d < 0.0f ? 1.0f : e;     // new term
    s = fmaf(s, f1, f2);
    m = fminf(m, v);
}
__device__ __forceinline__ float sm_final(float m, float s) {
    return fmaf(-SM_C, __builtin_amdgcn_logf(s), m);  // m - g*ln(s)
}

__device__ __forceinline__ float wave_reduce(float v) {
    #pragma unroll
    for (int o = 32; o > 0; o >>= 1) v += __shfl_down(v, o);
    return v;
}

// ---------------------------------------------------------------------------
// init: w0 = distances/(soft_adj+1e-4) * (1-eye); per-block partial loss sums
// part layout: [0..511]=loss_cost [512..1023]=entropy [1024..1535]=mask
//              [1536..2047]=utility (written by util_kernel)
// ---------------------------------------------------------------------------
__global__ __launch_bounds__(256) void init_kernel(
        const float* __restrict__ sa, const float* __restrict__ oa,
        const float* __restrict__ di, float* __restrict__ w,
        float* __restrict__ part) {
    float lc = 0.0f, en = 0.0f, mk = 0.0f;
    for (int idx = blockIdx.x * 256 + threadIdx.x; idx < N * N;
         idx += gridDim.x * 256) {
        int i = idx >> 9, j = idx & (N - 1);
        float s = sa[idx], d = di[idx];
        w[idx] = (i == j) ? 0.0f : d / (s + 1e-4f);
        lc = fmaf(s, d, lc);
        float inv = ((i == j) ? 1.0f : 0.0f) - s;
        float t2 = s * inv;
        en = fmaf(t2, t2, en);
        mk = fmaf(s, 1.0f - oa[idx], mk);
    }
    __shared__ float r[3][4];
    int wid = threadIdx.x >> 6, lane = threadIdx.x & 63;
    lc = wave_reduce(lc); en = wave_reduce(en); mk = wave_reduce(mk);
    if (lane == 0) { r[0][wid] = lc; r[1][wid] = en; r[2][wid] = mk; }
    __syncthreads();
    if (threadIdx.x == 0) {
        part[blockIdx.x]          = r[0][0] + r[0][1] + r[0][2] + r[0][3];
        part[512 + blockIdx.x]    = r[1][0] + r[1][1] + r[1][2] + r[1][3];
        part[1024 + blockIdx.x]   = r[2][0] + r[2][1] + r[2][2] + r[2][3];
    }
}

// ---------------------------------------------------------------------------
// fused panel: wave 0 computes exact TxT diag pivots (D or E half) into LDS,
// then all 256 threads run the panel chains.
// blocks 0,1 -> rowpiv[T][N] (thread = column j, needs E)
// blocks 2,3 -> colpiv[N][T] (thread = row i,    needs D)
// ---------------------------------------------------------------------------
__global__ __launch_bounds__(256) void panel_kernel(
        const float* __restrict__ w, float* __restrict__ rowpiv,
        float* __restrict__ colpiv, int k0) {
    __shared__ float P[T * T];
    __shared__ float WT[256][T + 1];
    const int t = threadIdx.x;
    const bool isRow = blockIdx.x < 2;
    const int base = (blockIdx.x & 1) * 256;

    if (!isRow && t >= 64) {
        // waves 1-3 stage w[base..base+255][k0..k0+31] while wave 0 does diag
        for (int idx = t - 64; idx < 256 * T; idx += 192) {
            int row = idx >> 5, c = idx & (T - 1);
            WT[row][c] = w[(base + row) * N + k0 + c];
        }
    }
    if (t < 64) {
        // diag: lanes 0..31 own col j' of D (D[k][j']=w^(k)[k0+k,k0+j']),
        //       lanes 32..63 own row i' of E (E[i'][k]=w^(k)[k0+i',k0+k])
        const bool isD = t < T;
        const int q = isD ? t : (t - T);
        float mst[T], sst[T];
        #pragma unroll
        for (int k = 0; k < T; ++k) {
            int rr = isD ? (k0 + k) : (k0 + q);
            int cc = isD ? (k0 + q) : (k0 + k);
            mst[k] = w[rr * N + cc];
            sst[k] = 1.0f;
        }
        const int srcbase = isD ? T : 0;
        #pragma unroll
        for (int mm = 0; mm < T; ++mm) {
            float val = sm_final(mst[mm], sst[mm]);
            // row blocks need E[i'][k] -> P[i'*T+k]; col blocks need D[m][j'] -> P[m*T+j']
            if (isD != isRow) {
                if (isD) P[mm * T + q] = val;   // D[mm][j']
                else     P[q * T + mm] = val;   // E[i'][mm]
            }
            #pragma unroll
            for (int k = mm + 1; k < T; ++k) {
                float o = __shfl(val, srcbase + k);
                sm_update(o + val, mst[k], sst[k]);
            }
        }
    }
    __syncthreads();

    float mst[T], sst[T];
    if (isRow) {
        const int j = base + t;
        #pragma unroll
        for (int k = 0; k < T; ++k) { mst[k] = w[(k0 + k) * N + j]; sst[k] = 1.0f; }
        #pragma unroll
        for (int mm = 0; mm < T; ++mm) {
            float val = sm_final(mst[mm], sst[mm]);
            rowpiv[mm * N + j] = val;              // coalesced
            #pragma unroll
            for (int k = mm + 1; k < T; ++k)
                sm_update(P[k * T + mm] + val, mst[k], sst[k]);  // E[k][mm]+rowpiv[mm][j]
        }
    } else {
        #pragma unroll
        for (int k = 0; k < T; ++k) { mst[k] = WT[t][k]; sst[k] = 1.0f; }
        float piv[T];
        #pragma unroll
        for (int mm = 0; mm < T; ++mm) {
            float val = sm_final(mst[mm], sst[mm]);
            piv[mm] = val;
            #pragma unroll
            for (int k = mm + 1; k < T; ++k)
                sm_update(val + P[mm * T + k], mst[k], sst[k]);  // colpiv[i][mm]+D[mm][k]
        }
        __syncthreads();
        #pragma unroll
        for (int k = 0; k < T; ++k) WT[t][k] = piv[k];
        __syncthreads();
        for (int idx = t; idx < 256 * T; idx += 256) {   // coalesced store
            int row = idx >> 5, c = idx & (T - 1);
            colpiv[(base + row) * T + c] = WT[row][c];
        }
    }
}

// ---------------------------------------------------------------------------
// sweep: apply the T-step chain uniformly to every element.
// grid 512 = 64 row-groups x 8 col-groups; tile 8x64; thread -> 2 elements.
// ---------------------------------------------------------------------------
__global__ __launch_bounds__(256) void sweep_kernel(
        float* __restrict__ w, const float* __restrict__ rowpiv,
        const float* __restrict__ colpiv) {
    const int tr = blockIdx.x >> 3, tc = blockIdx.x & 7;
    const int r0 = tr * 8, c0 = tc * 64;
    __shared__ float RP[T][64];
    __shared__ float CP[8][T];
    const int t = threadIdx.x;
    for (int idx = t; idx < T * 64; idx += 256) {
        int k = idx >> 6, c = idx & 63;
        RP[k][c] = rowpiv[k * N + c0 + c];
    }
    {
        int r = t >> 5, k = t & (T - 1);
        CP[r][k] = colpiv[(r0 + r) * T + k];
    }
    __syncthreads();
    const int rr = t >> 6;       // 0..3
    const int c = t & 63;
    float* wp0 = &w[(r0 + rr) * N + c0 + c];
    float* wp1 = &w[(r0 + rr + 4) * N + c0 + c];
    float m0 = *wp0, s0 = 1.0f;
    float m1 = *wp1, s1 = 1.0f;
    #pragma unroll
    for (int k = 0; k < T; ++k) {
        float rp = RP[k][c];
        sm_update(CP[rr][k] + rp, m0, s0);
        sm_update(CP[rr + 4][k] + rp, m1, s1);
    }
    *wp0 = sm_final(m0, s0);
    *wp1 = sm_final(m1, s1);
}

// ---------------------------------------------------------------------------
// utility-gain pass over final shortest paths (per-block partials, no atomics)
// ---------------------------------------------------------------------------
__global__ __launch_bounds__(256) void util_kernel(
        const float* __restrict__ w, const float* __restrict__ di,
        const float* __restrict__ fl, float* __restrict__ part) {
    float ug = 0.0f;
    for (int idx = blockIdx.x * 256 + threadIdx.x; idx < N * N;
         idx += gridDim.x * 256) {
        int i = idx >> 9, j = idx & (N - 1);
        float sp = w[idx], d = di[idx];
        float er = __expf(-0.005f * sp);      // exp(UTILITY_SCALE*sp*PRIORITY_RAIL)
        float eb = __expf(-0.01f * d);
        float choice = er / (er + eb);
        float x = d - 0.5f * sp;
        float elu = x > 0.0f ? x : (__expf(x) - 1.0f);
        float dsv = (i == j) ? 0.0f : (elu + 1.0f);
        ug = fmaf(fl[idx] * choice, dsv, ug);
    }
    __shared__ float r[4];
    int wid = threadIdx.x >> 6, lane = threadIdx.x & 63;
    ug = wave_reduce(ug);
    if (lane == 0) r[wid] = ug;
    __syncthreads();
    if (threadIdx.x == 0)
        part[1536 + blockIdx.x] = r[0] + r[1] + r[2] + r[3];
}

// ---------------------------------------------------------------------------
// final reduction of 4x512 partials + scale selection
// ---------------------------------------------------------------------------
__global__ __launch_bounds__(256) void combine_kernel(
        const float* __restrict__ part, const int* __restrict__ epoch,
        float* __restrict__ out) {
    __shared__ float red[4];
    int wid = threadIdx.x >> 6, lane = threadIdx.x & 63;
    const float* p = part + wid * 512;
    float v = 0.0f;
    #pragma unroll
    for (int i = 0; i < 8; ++i) v += p[lane + i * 64];
    v = wave_reduce(v);
    if (lane == 0) red[wid] = v;
    __syncthreads();
    if (threadIdx.x == 0) {
        int e = *epoch;
        // searchsorted([0,100], e, right) -> (e>=0)+(e>=100); levels {0.1,0.5,1.0}
        int idx = (e >= 0 ? 1 : 0) + (e >= 100 ? 1 : 0);
        float scale = idx == 0 ? 0.1f : (idx == 1 ? 0.5f : 1.0f);
        out[0] = red[0] + red[3] + scale * (red[1] + red[2]);
    }
}

extern "C" void kernel_launch(void* const* d_in, const int* in_sizes, int n_in,
                              void* d_out, int out_size, void* d_ws, size_t ws_size,
                              hipStream_t stream) {
    const float* sa = (const float*)d_in[0];
    const float* oa = (const float*)d_in[1];
    const float* di = (const float*)d_in[2];
    const float* fl = (const float*)d_in[3];
    const int* ep = (const int*)d_in[4];
    float* out = (float*)d_out;

    float* ws = (float*)d_ws;
    float* w      = ws;                 // 262144
    float* rowpiv = ws + 262144;        // 16384  (T x N)
    float* colpiv = ws + 278528;        // 16384  (N x T)
    float* part   = ws + 294912;        // 2048   (4 x 512 partials)

    init_kernel<<<512, 256, 0, stream>>>(sa, oa, di, w, part);
    for (int r = 0; r < NROUND; ++r) {
        int k0 = r * T;
        panel_kernel<<<4, 256, 0, stream>>>(w, rowpiv, colpiv, k0);
        sweep_kernel<<<512, 256, 0, stream>>>(w, rowpiv, colpiv);
    }
    util_kernel<<<512, 256, 0, stream>>>(w, di, fl, part);
    combine_kernel<<<1, 256, 0, stream>>>(part, ep, out);
}